// Round 10
// baseline (433.719 us; speedup 1.0000x reference)
//
#include <hip/hip_runtime.h>

// ---------------------------------------------------------------------------
// SimpleBiquadEQ: 10-band peaking-EQ cascade (IIR) over [32,2,262144] fp32.
// Round 12: r8 base (232.7 us, best) + moderate prefetch in fold/rewalk.
//  r9 post-mortem: nx[40] deep prefetch hit the 256-VGPR cap and spilled
//  (WRITE 89MB). But it confirmed fold/rewalk are MLP-starved (2 waves/CU,
//  ~5 lines in flight -> ~0.6-1 TB/s on a 21MB stream).
//  - scan_fold / scan_rewalk: 2-j-step ping-pong prefetch (float4 nx[2][10],
//    fully unrolled -> static indexing). Peak live ~150 VGPR < 256 cap.
//  - scan_ks2: nb[20]+matvec_acc step (r3/r6-validated; ~110 LDS ops/step).
//  - pass_eq<false/true>: byte-identical to r8 (validated, 54 us, VGPR 68).
// ---------------------------------------------------------------------------

#define B_   32
#define C_   2
#define S_   262144
#define NB   10
#define SEQ  64

#define F_LCH   64          // samples per chunk
#define F_PCH   4096        // chunks per sequence
#define F_G     8           // chunks per scan group
#define F_GRP   512         // groups per sequence

// T layout (float4 units): plane(seq,j,i) = ((seq*8 + j)*5 + i)*512, + g
// where chunk = 8*g + j.
// gbuf/sbuf layout (float4 units): (seq*5 + i)*512 + g (SoA planes)
#define T_FLOATS  5242880   // 64*40*512*4
#define G_FLOATS  655360    // 64*5*512*4

// ===========================================================================
// shared matvec helper (M col-major in LDS: M[c*20+r]); acc += M*v
// ===========================================================================
__device__ __forceinline__ void matvec_acc(const float* M,
                                           const float* v, float* acc) {
  #pragma unroll
  for (int c = 0; c < 20; c++) {
    float vc = v[c];
    const float4* col = (const float4*)&M[c*20];
    float4 c0 = col[0], c1 = col[1], c2 = col[2], c3 = col[3], c4 = col[4];
    acc[0]  = fmaf(c0.x, vc, acc[0]);  acc[1]  = fmaf(c0.y, vc, acc[1]);
    acc[2]  = fmaf(c0.z, vc, acc[2]);  acc[3]  = fmaf(c0.w, vc, acc[3]);
    acc[4]  = fmaf(c1.x, vc, acc[4]);  acc[5]  = fmaf(c1.y, vc, acc[5]);
    acc[6]  = fmaf(c1.z, vc, acc[6]);  acc[7]  = fmaf(c1.w, vc, acc[7]);
    acc[8]  = fmaf(c2.x, vc, acc[8]);  acc[9]  = fmaf(c2.y, vc, acc[9]);
    acc[10] = fmaf(c2.z, vc, acc[10]); acc[11] = fmaf(c2.w, vc, acc[11]);
    acc[12] = fmaf(c3.x, vc, acc[12]); acc[13] = fmaf(c3.y, vc, acc[13]);
    acc[14] = fmaf(c3.z, vc, acc[14]); acc[15] = fmaf(c3.w, vc, acc[15]);
    acc[16] = fmaf(c4.x, vc, acc[16]); acc[17] = fmaf(c4.y, vc, acc[17]);
    acc[18] = fmaf(c4.z, vc, acc[18]); acc[19] = fmaf(c4.w, vc, acc[19]);
  }
}

// per-band RBJ peaking coefficients (normalized, na1 = -a1, na2 = -a2)
__device__ __forceinline__ void peak_coefs(float f, float g, float Q,
                                           float& c0, float& c1, float& c2,
                                           float& c3, float& c4) {
  float w0 = 6.28318530717958648f * f / 44100.0f;
  float sw = sinf(w0), cw = cosf(w0);
  float alpha = sw / (2.0f * Q);
  float A = expf(g * 0.05756462732485114f);   // 10^(g/40)
  float aA = alpha * A, adA = alpha / A;
  float inv = 1.0f / (1.0f + adA);
  c0 = (1.0f + aA) * inv;
  c1 = -2.0f * cw * inv;
  c2 = (1.0f - aA) * inv;
  c3 = 2.0f * cw * inv;      // -a1
  c4 = -(1.0f - adA) * inv;  // -a2
}

// build A into bufA (400 floats, row-major) -- caller must sync before/after
__device__ __forceinline__ void build_A(const float* cfs, float* bufA,
                                        int tid) {
  if (tid < 20) {
    int c = tid;
    float rp = 0.0f;
    for (int k = 0; k < NB; k++) {
      float b0 = cfs[k*5+0], b1 = cfs[k*5+1], b2 = cfs[k*5+2];
      float na1 = cfs[k*5+3], na2 = cfs[k*5+4];
      float val = (k > 0) ? b0 * rp : 0.0f;
      if (k > 0) {
        if (c == 2*k-2) val += b1;
        if (c == 2*k-1) val += b2;
      }
      if (c == 2*k)   val += na1;
      if (c == 2*k+1) val += na2;
      bufA[2*k*20 + c] = val;
      rp = val;
      if (c == 2*k) bufA[(2*k+1)*20 + c] = 1.0f;
    }
  }
}

// ===========================================================================
// passes: 1 wave per wg, one 16 KB tile, coefs computed in-wave -> SGPRs.
// (byte-identical to validated round-8 build)
// ===========================================================================
template <bool WRITE_OUT>
__global__ __launch_bounds__(64) void pass_eq(
    const float* __restrict__ x,
    const float* __restrict__ freqs, const float* __restrict__ gains,
    const float* __restrict__ qs,
    float* __restrict__ t, float* __restrict__ out) {
  __shared__ __align__(16) float4 smem[1024];   // 16 KB tile
  const int seq = blockIdx.y;
  const int b = seq >> 1;
  const int lane = threadIdx.x;
  const int tile = blockIdx.x;               // 0..63
  const int chunk = tile * F_LCH + lane;     // seq-local chunk id
  const float* xseq = x + (size_t)seq * S_;

  // ---- stage tile: pre-swizzled global source, linear LDS dest ----
  const float4* gx = (const float4*)(xseq + (size_t)tile * 4096);
  #pragma unroll
  for (int it = 0; it < 16; it++) {
    const int f = it * 64 + lane;
    const int c = f >> 4;
    const int gi = (c << 4) | ((f & 15) ^ (c & 15));
    __builtin_amdgcn_global_load_lds(
        (const __attribute__((address_space(1))) void*)(gx + gi),
        (__attribute__((address_space(3))) void*)(smem + it * 64),
        16, 0, 0);
  }
  // ---- edge samples (x[-1], x[-2] of the tile) ----
  float2 pe = make_float2(0.f, 0.f);
  if (tile > 0) pe = *((const float2*)gx - 1);   // broadcast
  // ---- <true>: prefix state = T[chunk-1] (inclusive prefix of c-1) ----
  float4 st4[5];
  if constexpr (WRITE_OUT) {
    const int cm1 = (chunk > 0) ? chunk - 1 : 0;
    const int jj = cm1 & 7, gg = cm1 >> 3;
    const float4* sv = (const float4*)t + ((size_t)seq * 8 + jj) * 5 * 512 + gg;
    #pragma unroll
    for (int i = 0; i < 5; i++) st4[i] = sv[i * 512];
  }
  // ---- coefs in-wave: lane k<10 computes band k; readlane -> SGPRs ----
  float cc0 = 0.f, cc1 = 0.f, cc2 = 0.f, cc3 = 0.f, cc4 = 0.f;
  if (lane < NB) {
    int idx = b * NB + lane;
    peak_coefs(freqs[idx], gains[idx], qs[idx], cc0, cc1, cc2, cc3, cc4);
  }
  float b0[NB], b1[NB], b2[NB], na1[NB], na2[NB];
  #pragma unroll
  for (int k = 0; k < NB; k++) {
    b0[k]  = __uint_as_float(__builtin_amdgcn_readlane(__float_as_uint(cc0), k));
    b1[k]  = __uint_as_float(__builtin_amdgcn_readlane(__float_as_uint(cc1), k));
    b2[k]  = __uint_as_float(__builtin_amdgcn_readlane(__float_as_uint(cc2), k));
    na1[k] = __uint_as_float(__builtin_amdgcn_readlane(__float_as_uint(cc3), k));
    na2[k] = __uint_as_float(__builtin_amdgcn_readlane(__float_as_uint(cc4), k));
  }

  asm volatile("s_waitcnt vmcnt(0) lgkmcnt(0)" ::: "memory");
  __builtin_amdgcn_sched_barrier(0);

  // ---- init filter state ----
  float p[NB], q_[NB];
  if constexpr (WRITE_OUT) {
    const bool z = (chunk == 0);
    #pragma unroll
    for (int i = 0; i < 5; i++) {
      float4 a = st4[i];
      p[2*i]   = z ? 0.f : a.x;  q_[2*i]   = z ? 0.f : a.y;
      p[2*i+1] = z ? 0.f : a.z;  q_[2*i+1] = z ? 0.f : a.w;
    }
  } else {
    #pragma unroll
    for (int k = 0; k < NB; k++) { p[k] = 0.0f; q_[k] = 0.0f; }
  }
  // ---- x1/x2 init from neighbor chunk in LDS ----
  float x1, x2;
  if (lane == 0) {
    x1 = pe.y; x2 = pe.x;            // zeros when tile==0
  } else {
    float4 pv = smem[(lane-1)*16 + (15 ^ ((lane-1) & 15))];
    x2 = pv.z; x1 = pv.w;
  }
  // ---- filter: my chunk = lane, 16 float4 from LDS ----
  #pragma unroll 2
  for (int qq = 0; qq < 16; qq++) {
    const int slot = lane*16 + (qq ^ (lane & 15));
    float4 xv = smem[slot];
    float xin[4] = {xv.x, xv.y, xv.z, xv.w};
    float o[4];
    #pragma unroll
    for (int j = 0; j < 4; j++) {
      float u = xin[j], u1 = x1, u2 = x2;
      x2 = x1; x1 = xin[j];
      #pragma unroll
      for (int k = 0; k < NB; k++) {
        float v = fmaf(b0[k], u,
                  fmaf(b1[k], u1,
                  fmaf(b2[k], u2,
                  fmaf(na1[k], p[k], na2[k] * q_[k]))));
        u1 = p[k]; u2 = q_[k];
        q_[k] = p[k]; p[k] = v;
        u = v;
      }
      o[j] = u;
    }
    if (WRITE_OUT) smem[slot] = make_float4(o[0], o[1], o[2], o[3]);
  }
  if constexpr (WRITE_OUT) {
    asm volatile("" ::: "memory");   // keep ds_writes before store-phase reads
    float4* gy = (float4*)(out + (size_t)seq * S_ + (size_t)tile * 4096);
    #pragma unroll 4
    for (int it = 0; it < 16; it++) {
      int f = it * 64 + lane;
      int c = f >> 4, q = f & 15;
      gy[f] = smem[c*16 + (q ^ (c & 15))];
    }
  } else {
    // ---- T write (transposed planes) ----
    const int jj = chunk & 7, gg = chunk >> 3;
    float4* td = (float4*)t + ((size_t)seq * 8 + jj) * 5 * 512 + gg;
    td[0]    = make_float4(p[0], q_[0], p[1], q_[1]);
    td[512]  = make_float4(p[2], q_[2], p[3], q_[3]);
    td[1024] = make_float4(p[4], q_[4], p[5], q_[5]);
    td[1536] = make_float4(p[6], q_[6], p[7], q_[7]);
    td[2048] = make_float4(p[8], q_[8], p[9], q_[9]);
  }
}

// ===========================================================================
// scan_fold: 256 WGs x 128 thr, one group per thread.
// 2-j-step ping-pong prefetch (10 float4 per phase; ~150 live VGPR max).
// ===========================================================================
__global__ __launch_bounds__(128) void scan_fold(
    const float* __restrict__ t,
    const float* __restrict__ freqs, const float* __restrict__ gains,
    const float* __restrict__ qs, float* __restrict__ gbuf) {
  __shared__ float bufA[400], bufB[400];
  __shared__ __align__(16) float Msh[400];
  __shared__ float cfs[NB * 5];
  const int seq = blockIdx.y, b = seq >> 1, tid = threadIdx.x;
  const int g = blockIdx.x * 128 + tid;   // 0..511

  for (int e = tid; e < 400; e += 128) bufA[e] = 0.0f;
  if (tid < NB) {
    int idx = b * NB + tid;
    float c0, c1, c2, c3, c4;
    peak_coefs(freqs[idx], gains[idx], qs[idx], c0, c1, c2, c3, c4);
    cfs[tid*5+0] = c0; cfs[tid*5+1] = c1; cfs[tid*5+2] = c2;
    cfs[tid*5+3] = c3; cfs[tid*5+4] = c4;
  }
  __syncthreads();
  build_A(cfs, bufA, tid);
  __syncthreads();
  {
    float* cur = bufA;
    float* nxt = bufB;
    for (int j = 1; j <= 6; j++) {          // cur becomes A^64
      for (int e = tid; e < 400; e += 128) {
        int r = e / 20, c = e % 20;
        float acc = 0.0f;
        #pragma unroll
        for (int k = 0; k < 20; k++) acc = fmaf(cur[r*20+k], cur[k*20+c], acc);
        nxt[e] = acc;
      }
      __syncthreads();
      { float* t_ = cur; cur = nxt; nxt = t_; }
    }
    for (int e = tid; e < 400; e += 128)
      Msh[(e % 20) * 20 + e / 20] = cur[e];  // col-major
  }
  __syncthreads();

  // ---- fold with 2-step ping-pong prefetch ----
  const float4* tb = (const float4*)t + (size_t)seq * 40 * 512 + g;
  float s[20];
  #pragma unroll
  for (int r = 0; r < 20; r++) s[r] = 0.0f;
  float4 nx[2][10];
  #pragma unroll
  for (int i = 0; i < 10; i++) nx[0][i] = tb[(size_t)i * 512];   // j=0,1
  #pragma unroll
  for (int jp = 0; jp < 4; jp++) {          // fully unrolled -> static idx
    const int cur = jp & 1, nxt = cur ^ 1;
    if (jp < 3) {
      const float4* np = tb + (size_t)(jp + 1) * 10 * 512;
      #pragma unroll
      for (int i = 0; i < 10; i++) nx[nxt][i] = np[(size_t)i * 512];
    }
    #pragma unroll
    for (int h = 0; h < 2; h++) {
      float ns[20];
      #pragma unroll
      for (int i = 0; i < 5; i++) {
        float4 a = nx[cur][h*5 + i];
        ns[4*i] = a.x; ns[4*i+1] = a.y; ns[4*i+2] = a.z; ns[4*i+3] = a.w;
      }
      matvec_acc(Msh, s, ns);
      #pragma unroll
      for (int r = 0; r < 20; r++) s[r] = ns[r];
    }
  }
  float4* gw = (float4*)gbuf + (size_t)seq * 5 * 512 + g;
  gw[0]    = make_float4(s[0],  s[1],  s[2],  s[3]);
  gw[512]  = make_float4(s[4],  s[5],  s[6],  s[7]);
  gw[1024] = make_float4(s[8],  s[9],  s[10], s[11]);
  gw[1536] = make_float4(s[12], s[13], s[14], s[15]);
  gw[2048] = make_float4(s[16], s[17], s[18], s[19]);
}

// ===========================================================================
// scan_ks2: 64 WGs x 512 thr, KS ONLY. nb[20] + matvec_acc step
// (r3/r6-validated shape, ~70 live VGPR, no spill at the 128 cap).
// Writes EXCLUSIVE group prefixes to sbuf (SoA planes).
// ===========================================================================
__global__ __launch_bounds__(512) void scan_ks2(
    const float* __restrict__ gbuf, float* __restrict__ sbuf,
    const float* __restrict__ freqs, const float* __restrict__ gains,
    const float* __restrict__ qs) {
  __shared__ float2 h2[10 * 512];                 // 40 KB
  __shared__ __align__(16) float Ks[9][400];      // KS matrices col-major
  __shared__ float bufA[400], bufB[400];
  __shared__ float cfs[NB * 5];
  const int seq = blockIdx.x, b = seq >> 1, i = threadIdx.x;

  for (int e = i; e < 400; e += 512) bufA[e] = 0.0f;
  if (i < NB) {
    int idx = b * NB + i;
    float c0, c1, c2, c3, c4;
    peak_coefs(freqs[idx], gains[idx], qs[idx], c0, c1, c2, c3, c4);
    cfs[i*5+0] = c0; cfs[i*5+1] = c1; cfs[i*5+2] = c2;
    cfs[i*5+3] = c3; cfs[i*5+4] = c4;
  }
  __syncthreads();
  build_A(cfs, bufA, i);
  __syncthreads();
  {
    float* cur = bufA;
    float* nxt = bufB;
    for (int j = 1; j <= 17; j++) {
      for (int e = i; e < 400; e += 512) {
        int r = e / 20, c = e % 20;
        float acc = 0.0f;
        #pragma unroll
        for (int k = 0; k < 20; k++) acc = fmaf(cur[r*20+k], cur[k*20+c], acc);
        nxt[e] = acc;
      }
      __syncthreads();
      { float* t_ = cur; cur = nxt; nxt = t_; }
      if (j >= 9) {
        float* dst = Ks[j - 9];                   // A^(512*2^(j-9))
        for (int e = i; e < 400; e += 512)
          dst[(e % 20) * 20 + e / 20] = cur[e];   // col-major
      }
    }
  }
  __syncthreads();

  // ---- load own group total (coalesced SoA planes) -> h2 ----
  float own[20];
  {
    const float4* gv = (const float4*)gbuf + (size_t)seq * 5 * 512 + i;
    #pragma unroll
    for (int k = 0; k < 5; k++) {
      float4 a = gv[k * 512];
      own[4*k] = a.x; own[4*k+1] = a.y; own[4*k+2] = a.z; own[4*k+3] = a.w;
    }
  }
  #pragma unroll
  for (int r2 = 0; r2 < 10; r2++)
    h2[r2*512 + i] = make_float2(own[2*r2], own[2*r2+1]);
  __syncthreads();

  // ---- Kogge-Stone over 512 group totals ----
  #pragma unroll 1
  for (int st = 0; st < 9; st++) {
    const int d = 1 << st;
    const float* K = Ks[st];
    const bool doA = (i >= d);
    float nb[20];
    if (doA) {
      #pragma unroll
      for (int r2 = 0; r2 < 10; r2++) {
        float2 v = h2[r2*512 + i - d];
        nb[2*r2] = v.x; nb[2*r2+1] = v.y;
      }
    }
    __syncthreads();               // all reads done before any write
    if (doA) {
      matvec_acc(K, nb, own);
      #pragma unroll
      for (int r2 = 0; r2 < 10; r2++)
        h2[r2*512 + i] = make_float2(own[2*r2], own[2*r2+1]);
    }
    __syncthreads();               // writes done before next step's reads
  }

  // ---- exclusive shift -> sbuf (SoA planes) ----
  float4* sw = (float4*)sbuf + (size_t)seq * 5 * 512 + i;
  if (i > 0) {
    #pragma unroll
    for (int k = 0; k < 5; k++) {
      float2 a = h2[(2*k)*512 + i - 1];
      float2 c = h2[(2*k+1)*512 + i - 1];
      sw[k * 512] = make_float4(a.x, a.y, c.x, c.y);
    }
  } else {
    #pragma unroll
    for (int k = 0; k < 5; k++) sw[k * 512] = make_float4(0.f, 0.f, 0.f, 0.f);
  }
}

// ===========================================================================
// scan_rewalk: 256 WGs x 128 thr, one group per thread.
// 2-j-step ping-pong prefetch; T := inclusive per-chunk prefixes in place.
// ===========================================================================
__global__ __launch_bounds__(128) void scan_rewalk(
    float* __restrict__ t, const float* __restrict__ sbuf,
    const float* __restrict__ freqs, const float* __restrict__ gains,
    const float* __restrict__ qs) {
  __shared__ float bufA[400], bufB[400];
  __shared__ __align__(16) float Msh[400];
  __shared__ float cfs[NB * 5];
  const int seq = blockIdx.y, b = seq >> 1, tid = threadIdx.x;
  const int g = blockIdx.x * 128 + tid;   // 0..511

  for (int e = tid; e < 400; e += 128) bufA[e] = 0.0f;
  if (tid < NB) {
    int idx = b * NB + tid;
    float c0, c1, c2, c3, c4;
    peak_coefs(freqs[idx], gains[idx], qs[idx], c0, c1, c2, c3, c4);
    cfs[tid*5+0] = c0; cfs[tid*5+1] = c1; cfs[tid*5+2] = c2;
    cfs[tid*5+3] = c3; cfs[tid*5+4] = c4;
  }
  __syncthreads();
  build_A(cfs, bufA, tid);
  __syncthreads();
  {
    float* cur = bufA;
    float* nxt = bufB;
    for (int j = 1; j <= 6; j++) {          // cur becomes A^64
      for (int e = tid; e < 400; e += 128) {
        int r = e / 20, c = e % 20;
        float acc = 0.0f;
        #pragma unroll
        for (int k = 0; k < 20; k++) acc = fmaf(cur[r*20+k], cur[k*20+c], acc);
        nxt[e] = acc;
      }
      __syncthreads();
      { float* t_ = cur; cur = nxt; nxt = t_; }
    }
    for (int e = tid; e < 400; e += 128)
      Msh[(e % 20) * 20 + e / 20] = cur[e];  // col-major
  }
  __syncthreads();

  // ---- exclusive group prefix ----
  float s[20];
  {
    const float4* sv = (const float4*)sbuf + (size_t)seq * 5 * 512 + g;
    #pragma unroll
    for (int i = 0; i < 5; i++) {
      float4 a = sv[i * 512];
      s[4*i] = a.x; s[4*i+1] = a.y; s[4*i+2] = a.z; s[4*i+3] = a.w;
    }
  }
  // ---- rewalk with 2-step ping-pong prefetch ----
  float4* tw = (float4*)t + (size_t)seq * 40 * 512 + g;
  float4 nx[2][10];
  #pragma unroll
  for (int i = 0; i < 10; i++) nx[0][i] = tw[(size_t)i * 512];   // j=0,1
  #pragma unroll
  for (int jp = 0; jp < 4; jp++) {          // fully unrolled -> static idx
    const int cur = jp & 1, nxt = cur ^ 1;
    if (jp < 3) {
      const float4* np = tw + (size_t)(jp + 1) * 10 * 512;
      #pragma unroll
      for (int i = 0; i < 10; i++) nx[nxt][i] = np[(size_t)i * 512];
    }
    #pragma unroll
    for (int h = 0; h < 2; h++) {
      float ns[20];
      #pragma unroll
      for (int i = 0; i < 5; i++) {
        float4 a = nx[cur][h*5 + i];
        ns[4*i] = a.x; ns[4*i+1] = a.y; ns[4*i+2] = a.z; ns[4*i+3] = a.w;
      }
      matvec_acc(Msh, s, ns);
      #pragma unroll
      for (int r = 0; r < 20; r++) s[r] = ns[r];
      float4* wp = tw + (size_t)((jp*2 + h) * 5) * 512;
      wp[0]    = make_float4(s[0],  s[1],  s[2],  s[3]);
      wp[512]  = make_float4(s[4],  s[5],  s[6],  s[7]);
      wp[1024] = make_float4(s[8],  s[9],  s[10], s[11]);
      wp[1536] = make_float4(s[12], s[13], s[14], s[15]);
      wp[2048] = make_float4(s[16], s[17], s[18], s[19]);
    }
  }
}

// ===========================================================================
extern "C" void kernel_launch(void* const* d_in, const int* in_sizes, int n_in,
                              void* d_out, int out_size, void* d_ws, size_t ws_size,
                              hipStream_t stream) {
  const float* audio = (const float*)d_in[0];
  const float* freqs = (const float*)d_in[1];
  const float* gains = (const float*)d_in[2];
  const float* qs    = (const float*)d_in[3];
  float* out  = (float*)d_out;
  float* t    = (float*)d_ws;                         // 21 MB
  float* gbuf = (float*)d_ws + T_FLOATS;              // 2.6 MB
  float* sbuf = (float*)d_ws + T_FLOATS + G_FLOATS;   // 2.6 MB

  hipLaunchKernelGGL((pass_eq<false>), dim3(F_PCH / F_LCH, SEQ), dim3(64), 0,
                     stream, audio, freqs, gains, qs, t, (float*)nullptr);
  hipLaunchKernelGGL(scan_fold, dim3(F_GRP / 128, SEQ), dim3(128), 0, stream,
                     t, freqs, gains, qs, gbuf);
  hipLaunchKernelGGL(scan_ks2, dim3(SEQ), dim3(512), 0, stream,
                     gbuf, sbuf, freqs, gains, qs);
  hipLaunchKernelGGL(scan_rewalk, dim3(F_GRP / 128, SEQ), dim3(128), 0, stream,
                     t, sbuf, freqs, gains, qs);
  hipLaunchKernelGGL((pass_eq<true>), dim3(F_PCH / F_LCH, SEQ), dim3(64), 0,
                     stream, audio, freqs, gains, qs, t, out);
}

// Round 12
// 248.729 us; speedup vs baseline: 1.7437x; 1.7437x over previous
//
#include <hip/hip_runtime.h>

// ---------------------------------------------------------------------------
// SimpleBiquadEQ: 10-band peaking-EQ cascade (IIR) over [32,2,262144] fp32.
// Round 13 (resubmit; round-11 bench was a container-acquisition failure,
// same infra signature as round 5 which passed on resubmission):
//  - pass_head: r8 pass<false> verbatim (54 us, VGPR 68, validated).
//  - scan_fold: r8 verbatim + designated WGs publish A^64/128/256 col-major
//    to a powers buffer (2 extra squarings; replaces any setup kernel).
//  - scan_ks2: r8 verbatim (SoA gbuf/sbuf, self-built matrices).
//  - pass_tail: r8 filter + r7-VALIDATED in-register init: w = (lanem==0 ?
//    sbuf[g] : T[c-1]) then 3 segmented-KS shuffle steps (A^64/128/256 from
//    LDS) reconstruct the inclusive prefix of chunk c-1. Rewalk kernel and
//    its 21MB T write ELIMINATED. r7 measured this pass shape: 82us, VGPR
//    240, no spill, absmax 0.1484.
// ---------------------------------------------------------------------------

#define B_   32
#define C_   2
#define S_   262144
#define NB   10
#define SEQ  64

#define F_LCH   64          // samples per chunk
#define F_PCH   4096        // chunks per sequence
#define F_G     8           // chunks per scan group
#define F_GRP   512         // groups per sequence

// T layout (float4 units): plane(seq,j,i) = ((seq*8 + j)*5 + i)*512, + g
// where chunk = 8*g + j.
// gbuf/sbuf layout (float4 units): (seq*5 + i)*512 + g (SoA planes)
// powers layout: per batch b, 1280 floats: [A^64 | A^128 | A^256] col-major
#define T_FLOATS  5242880   // 64*40*512*4
#define G_FLOATS  655360    // 64*5*512*4
#define PW_FLOATS 40960     // 32*1280

// ===========================================================================
// shared matvec helper (M col-major: M[c*20+r]); acc += M*v
// ===========================================================================
__device__ __forceinline__ void matvec_acc(const float* M,
                                           const float* v, float* acc) {
  #pragma unroll
  for (int c = 0; c < 20; c++) {
    float vc = v[c];
    const float4* col = (const float4*)&M[c*20];
    float4 c0 = col[0], c1 = col[1], c2 = col[2], c3 = col[3], c4 = col[4];
    acc[0]  = fmaf(c0.x, vc, acc[0]);  acc[1]  = fmaf(c0.y, vc, acc[1]);
    acc[2]  = fmaf(c0.z, vc, acc[2]);  acc[3]  = fmaf(c0.w, vc, acc[3]);
    acc[4]  = fmaf(c1.x, vc, acc[4]);  acc[5]  = fmaf(c1.y, vc, acc[5]);
    acc[6]  = fmaf(c1.z, vc, acc[6]);  acc[7]  = fmaf(c1.w, vc, acc[7]);
    acc[8]  = fmaf(c2.x, vc, acc[8]);  acc[9]  = fmaf(c2.y, vc, acc[9]);
    acc[10] = fmaf(c2.z, vc, acc[10]); acc[11] = fmaf(c2.w, vc, acc[11]);
    acc[12] = fmaf(c3.x, vc, acc[12]); acc[13] = fmaf(c3.y, vc, acc[13]);
    acc[14] = fmaf(c3.z, vc, acc[14]); acc[15] = fmaf(c3.w, vc, acc[15]);
    acc[16] = fmaf(c4.x, vc, acc[16]); acc[17] = fmaf(c4.y, vc, acc[17]);
    acc[18] = fmaf(c4.z, vc, acc[18]); acc[19] = fmaf(c4.w, vc, acc[19]);
  }
}

// one masked Kogge-Stone step over 8-lane segments: s += M * s[lane-d]
// (only where (lane&7) >= d)  -- r7-validated
__device__ __forceinline__ void ks_step(float* s, const float* M, int d,
                                        int lanem) {
  float t[20];
  #pragma unroll
  for (int r = 0; r < 20; r++) t[r] = __shfl_up(s[r], d, 64);
  float ns[20];
  #pragma unroll
  for (int r = 0; r < 20; r++) ns[r] = s[r];
  matvec_acc(M, t, ns);
  const bool c = (lanem >= d);
  #pragma unroll
  for (int r = 0; r < 20; r++) s[r] = c ? ns[r] : s[r];
}

// per-band RBJ peaking coefficients (normalized, na1 = -a1, na2 = -a2)
__device__ __forceinline__ void peak_coefs(float f, float g, float Q,
                                           float& c0, float& c1, float& c2,
                                           float& c3, float& c4) {
  float w0 = 6.28318530717958648f * f / 44100.0f;
  float sw = sinf(w0), cw = cosf(w0);
  float alpha = sw / (2.0f * Q);
  float A = expf(g * 0.05756462732485114f);   // 10^(g/40)
  float aA = alpha * A, adA = alpha / A;
  float inv = 1.0f / (1.0f + adA);
  c0 = (1.0f + aA) * inv;
  c1 = -2.0f * cw * inv;
  c2 = (1.0f - aA) * inv;
  c3 = 2.0f * cw * inv;      // -a1
  c4 = -(1.0f - adA) * inv;  // -a2
}

// build A into bufA (400 floats, row-major) -- caller must sync before/after
__device__ __forceinline__ void build_A(const float* cfs, float* bufA,
                                        int tid) {
  if (tid < 20) {
    int c = tid;
    float rp = 0.0f;
    for (int k = 0; k < NB; k++) {
      float b0 = cfs[k*5+0], b1 = cfs[k*5+1], b2 = cfs[k*5+2];
      float na1 = cfs[k*5+3], na2 = cfs[k*5+4];
      float val = (k > 0) ? b0 * rp : 0.0f;
      if (k > 0) {
        if (c == 2*k-2) val += b1;
        if (c == 2*k-1) val += b2;
      }
      if (c == 2*k)   val += na1;
      if (c == 2*k+1) val += na2;
      bufA[2*k*20 + c] = val;
      rp = val;
      if (c == 2*k) bufA[(2*k+1)*20 + c] = 1.0f;
    }
  }
}

// in-wave coefs: lane k<10 computes band k; readlane -> SGPRs
__device__ __forceinline__ void wave_coefs(
    const float* freqs, const float* gains, const float* qs, int b, int lane,
    float* b0, float* b1, float* b2, float* na1, float* na2) {
  float cc0 = 0.f, cc1 = 0.f, cc2 = 0.f, cc3 = 0.f, cc4 = 0.f;
  if (lane < NB) {
    int idx = b * NB + lane;
    peak_coefs(freqs[idx], gains[idx], qs[idx], cc0, cc1, cc2, cc3, cc4);
  }
  #pragma unroll
  for (int k = 0; k < NB; k++) {
    b0[k]  = __uint_as_float(__builtin_amdgcn_readlane(__float_as_uint(cc0), k));
    b1[k]  = __uint_as_float(__builtin_amdgcn_readlane(__float_as_uint(cc1), k));
    b2[k]  = __uint_as_float(__builtin_amdgcn_readlane(__float_as_uint(cc2), k));
    na1[k] = __uint_as_float(__builtin_amdgcn_readlane(__float_as_uint(cc3), k));
    na2[k] = __uint_as_float(__builtin_amdgcn_readlane(__float_as_uint(cc4), k));
  }
}

// ===========================================================================
// pass_head: r8 pass_eq<false> verbatim (lean, 16 KB tile, writes T).
// ===========================================================================
__global__ __launch_bounds__(64) void pass_head(
    const float* __restrict__ x,
    const float* __restrict__ freqs, const float* __restrict__ gains,
    const float* __restrict__ qs, float* __restrict__ t) {
  __shared__ __align__(16) float4 smem[1024];   // 16 KB tile
  const int seq = blockIdx.y;
  const int b = seq >> 1;
  const int lane = threadIdx.x;
  const int tile = blockIdx.x;               // 0..63
  const int chunk = tile * F_LCH + lane;     // seq-local chunk id
  const float* xseq = x + (size_t)seq * S_;

  const float4* gx = (const float4*)(xseq + (size_t)tile * 4096);
  #pragma unroll
  for (int it = 0; it < 16; it++) {
    const int f = it * 64 + lane;
    const int c = f >> 4;
    const int gi = (c << 4) | ((f & 15) ^ (c & 15));
    __builtin_amdgcn_global_load_lds(
        (const __attribute__((address_space(1))) void*)(gx + gi),
        (__attribute__((address_space(3))) void*)(smem + it * 64),
        16, 0, 0);
  }
  float2 pe = make_float2(0.f, 0.f);
  if (tile > 0) pe = *((const float2*)gx - 1);   // broadcast

  float b0[NB], b1[NB], b2[NB], na1[NB], na2[NB];
  wave_coefs(freqs, gains, qs, b, lane, b0, b1, b2, na1, na2);

  asm volatile("s_waitcnt vmcnt(0) lgkmcnt(0)" ::: "memory");
  __builtin_amdgcn_sched_barrier(0);

  float p[NB], q_[NB];
  #pragma unroll
  for (int k = 0; k < NB; k++) { p[k] = 0.0f; q_[k] = 0.0f; }
  float x1, x2;
  if (lane == 0) {
    x1 = pe.y; x2 = pe.x;            // zeros when tile==0
  } else {
    float4 pv = smem[(lane-1)*16 + (15 ^ ((lane-1) & 15))];
    x2 = pv.z; x1 = pv.w;
  }
  #pragma unroll 2
  for (int qq = 0; qq < 16; qq++) {
    const int slot = lane*16 + (qq ^ (lane & 15));
    float4 xv = smem[slot];
    float xin[4] = {xv.x, xv.y, xv.z, xv.w};
    #pragma unroll
    for (int j = 0; j < 4; j++) {
      float u = xin[j], u1 = x1, u2 = x2;
      x2 = x1; x1 = xin[j];
      #pragma unroll
      for (int k = 0; k < NB; k++) {
        float v = fmaf(b0[k], u,
                  fmaf(b1[k], u1,
                  fmaf(b2[k], u2,
                  fmaf(na1[k], p[k], na2[k] * q_[k]))));
        u1 = p[k]; u2 = q_[k];
        q_[k] = p[k]; p[k] = v;
        u = v;
      }
    }
  }
  // ---- T write (transposed planes) ----
  const int jj = chunk & 7, gg = chunk >> 3;
  float4* td = (float4*)t + ((size_t)seq * 8 + jj) * 5 * 512 + gg;
  td[0]    = make_float4(p[0], q_[0], p[1], q_[1]);
  td[512]  = make_float4(p[2], q_[2], p[3], q_[3]);
  td[1024] = make_float4(p[4], q_[4], p[5], q_[5]);
  td[1536] = make_float4(p[6], q_[6], p[7], q_[7]);
  td[2048] = make_float4(p[8], q_[8], p[9], q_[9]);
}

// ===========================================================================
// scan_fold: 256 WGs x 128 thr, one group per thread (r8 verbatim) +
// designated WGs (bid.x==0, even seq) publish A^64/128/256 col-major.
// ===========================================================================
__global__ __launch_bounds__(128) void scan_fold(
    const float* __restrict__ t,
    const float* __restrict__ freqs, const float* __restrict__ gains,
    const float* __restrict__ qs, float* __restrict__ gbuf,
    float* __restrict__ powers) {
  __shared__ float bufA[400], bufB[400];
  __shared__ __align__(16) float Msh[400];
  __shared__ float cfs[NB * 5];
  const int seq = blockIdx.y, b = seq >> 1, tid = threadIdx.x;
  const int g = blockIdx.x * 128 + tid;   // 0..511

  for (int e = tid; e < 400; e += 128) bufA[e] = 0.0f;
  if (tid < NB) {
    int idx = b * NB + tid;
    float c0, c1, c2, c3, c4;
    peak_coefs(freqs[idx], gains[idx], qs[idx], c0, c1, c2, c3, c4);
    cfs[tid*5+0] = c0; cfs[tid*5+1] = c1; cfs[tid*5+2] = c2;
    cfs[tid*5+3] = c3; cfs[tid*5+4] = c4;
  }
  __syncthreads();
  build_A(cfs, bufA, tid);
  __syncthreads();
  float* cur = bufA;
  float* nxt = bufB;
  for (int j = 1; j <= 6; j++) {          // cur becomes A^64
    for (int e = tid; e < 400; e += 128) {
      int r = e / 20, c = e % 20;
      float acc = 0.0f;
      #pragma unroll
      for (int k = 0; k < 20; k++) acc = fmaf(cur[r*20+k], cur[k*20+c], acc);
      nxt[e] = acc;
    }
    __syncthreads();
    { float* t_ = cur; cur = nxt; nxt = t_; }
  }
  for (int e = tid; e < 400; e += 128)
    Msh[(e % 20) * 20 + e / 20] = cur[e];  // col-major
  __syncthreads();

  // ---- designated WGs publish A^64/128/256 to powers (col-major) ----
  if (blockIdx.x == 0 && (seq & 1) == 0) {
    float* pwb = powers + (size_t)b * 1280;
    for (int e = tid; e < 400; e += 128)
      pwb[(e % 20) * 20 + e / 20] = cur[e];              // A^64
    for (int sq = 0; sq < 2; sq++) {                     // -> A^128, A^256
      for (int e = tid; e < 400; e += 128) {
        int r = e / 20, c = e % 20;
        float acc = 0.0f;
        #pragma unroll
        for (int k = 0; k < 20; k++) acc = fmaf(cur[r*20+k], cur[k*20+c], acc);
        nxt[e] = acc;
      }
      __syncthreads();
      { float* t_ = cur; cur = nxt; nxt = t_; }
      for (int e = tid; e < 400; e += 128)
        pwb[(sq + 1) * 400 + (e % 20) * 20 + e / 20] = cur[e];
      __syncthreads();
    }
  }

  // ---- fold (r8 verbatim: 1-deep prefetch) ----
  const float4* tb = (const float4*)t + (size_t)seq * 40 * 512 + g;
  float s[20];
  #pragma unroll
  for (int r = 0; r < 20; r++) s[r] = 0.0f;
  float4 nx[5];
  #pragma unroll
  for (int i = 0; i < 5; i++) nx[i] = tb[i * 512];
  #pragma unroll 1
  for (int j = 0; j < F_G; j++) {
    float ns[20];
    #pragma unroll
    for (int i = 0; i < 5; i++) {
      float4 a = nx[i];
      ns[4*i] = a.x; ns[4*i+1] = a.y; ns[4*i+2] = a.z; ns[4*i+3] = a.w;
    }
    if (j < F_G - 1) {
      const float4* np = tb + (size_t)(j + 1) * 5 * 512;
      #pragma unroll
      for (int i = 0; i < 5; i++) nx[i] = np[i * 512];
    }
    matvec_acc(Msh, s, ns);
    #pragma unroll
    for (int r = 0; r < 20; r++) s[r] = ns[r];
  }
  float4* gw = (float4*)gbuf + (size_t)seq * 5 * 512 + g;
  gw[0]    = make_float4(s[0],  s[1],  s[2],  s[3]);
  gw[512]  = make_float4(s[4],  s[5],  s[6],  s[7]);
  gw[1024] = make_float4(s[8],  s[9],  s[10], s[11]);
  gw[1536] = make_float4(s[12], s[13], s[14], s[15]);
  gw[2048] = make_float4(s[16], s[17], s[18], s[19]);
}

// ===========================================================================
// scan_ks2: 64 WGs x 512 thr, KS ONLY (r8 verbatim).
// Writes EXCLUSIVE group prefixes to sbuf (SoA planes).
// ===========================================================================
__global__ __launch_bounds__(512) void scan_ks2(
    const float* __restrict__ gbuf, float* __restrict__ sbuf,
    const float* __restrict__ freqs, const float* __restrict__ gains,
    const float* __restrict__ qs) {
  __shared__ float2 h2[10 * 512];                 // 40 KB
  __shared__ __align__(16) float Ks[9][400];      // KS matrices col-major
  __shared__ float bufA[400], bufB[400];
  __shared__ float cfs[NB * 5];
  const int seq = blockIdx.x, b = seq >> 1, i = threadIdx.x;

  for (int e = i; e < 400; e += 512) bufA[e] = 0.0f;
  if (i < NB) {
    int idx = b * NB + i;
    float c0, c1, c2, c3, c4;
    peak_coefs(freqs[idx], gains[idx], qs[idx], c0, c1, c2, c3, c4);
    cfs[i*5+0] = c0; cfs[i*5+1] = c1; cfs[i*5+2] = c2;
    cfs[i*5+3] = c3; cfs[i*5+4] = c4;
  }
  __syncthreads();
  build_A(cfs, bufA, i);
  __syncthreads();
  {
    float* cur = bufA;
    float* nxt = bufB;
    for (int j = 1; j <= 17; j++) {
      for (int e = i; e < 400; e += 512) {
        int r = e / 20, c = e % 20;
        float acc = 0.0f;
        #pragma unroll
        for (int k = 0; k < 20; k++) acc = fmaf(cur[r*20+k], cur[k*20+c], acc);
        nxt[e] = acc;
      }
      __syncthreads();
      { float* t_ = cur; cur = nxt; nxt = t_; }
      if (j >= 9) {
        float* dst = Ks[j - 9];                   // A^(512*2^(j-9))
        for (int e = i; e < 400; e += 512)
          dst[(e % 20) * 20 + e / 20] = cur[e];   // col-major
      }
    }
  }
  __syncthreads();

  float own[20];
  {
    const float4* gv = (const float4*)gbuf + (size_t)seq * 5 * 512 + i;
    #pragma unroll
    for (int k = 0; k < 5; k++) {
      float4 a = gv[k * 512];
      own[4*k] = a.x; own[4*k+1] = a.y; own[4*k+2] = a.z; own[4*k+3] = a.w;
    }
  }
  #pragma unroll
  for (int r2 = 0; r2 < 10; r2++)
    h2[r2*512 + i] = make_float2(own[2*r2], own[2*r2+1]);
  __syncthreads();

  #pragma unroll 1
  for (int st = 0; st < 9; st++) {
    const int d = 1 << st;
    const float* K = Ks[st];
    const bool doA = (i >= d);
    float nb[20];
    if (doA) {
      #pragma unroll
      for (int r2 = 0; r2 < 10; r2++) {
        float2 v = h2[r2*512 + i - d];
        nb[2*r2] = v.x; nb[2*r2+1] = v.y;
      }
    }
    __syncthreads();               // all reads done before any write
    if (doA) {
      matvec_acc(K, nb, own);
      #pragma unroll
      for (int r2 = 0; r2 < 10; r2++)
        h2[r2*512 + i] = make_float2(own[2*r2], own[2*r2+1]);
    }
    __syncthreads();               // writes done before next step's reads
  }

  float4* sw = (float4*)sbuf + (size_t)seq * 5 * 512 + i;
  if (i > 0) {
    #pragma unroll
    for (int k = 0; k < 5; k++) {
      float2 a = h2[(2*k)*512 + i - 1];
      float2 c = h2[(2*k+1)*512 + i - 1];
      sw[k * 512] = make_float4(a.x, a.y, c.x, c.y);
    }
  } else {
    #pragma unroll
    for (int k = 0; k < 5; k++) sw[k * 512] = make_float4(0.f, 0.f, 0.f, 0.f);
  }
}

// ===========================================================================
// pass_tail: filter + in-register init (r7-validated): w = (lanem==0 ?
// sbuf[g] : T[c-1]); 3 segmented-KS steps reconstruct prefix(c-1).
// ===========================================================================
__global__ __launch_bounds__(64) void pass_tail(
    const float* __restrict__ x,
    const float* __restrict__ freqs, const float* __restrict__ gains,
    const float* __restrict__ qs,
    const float* __restrict__ t, const float* __restrict__ sbuf,
    const float* __restrict__ powers, float* __restrict__ out) {
  __shared__ __align__(16) float4 smem[1024 + 320];   // tile + matrices
  const int seq = blockIdx.y;
  const int b = seq >> 1;
  const int lane = threadIdx.x;
  const int lanem = lane & 7;
  const int tile = blockIdx.x;               // 0..63
  const int chunk = tile * F_LCH + lane;
  const float* xseq = x + (size_t)seq * S_;

  // ---- stage matrices: 320 float4 (A^64/128/256 col-major) ----
  const float4* pwv4 = (const float4*)powers + (size_t)b * 320;
  #pragma unroll
  for (int it = 0; it < 5; it++) {
    __builtin_amdgcn_global_load_lds(
        (const __attribute__((address_space(1))) void*)(pwv4 + it * 64 + lane),
        (__attribute__((address_space(3))) void*)(smem + 1024 + it * 64),
        16, 0, 0);
  }
  // ---- stage tile ----
  const float4* gx = (const float4*)(xseq + (size_t)tile * 4096);
  #pragma unroll
  for (int it = 0; it < 16; it++) {
    const int f = it * 64 + lane;
    const int c = f >> 4;
    const int gi = (c << 4) | ((f & 15) ^ (c & 15));
    __builtin_amdgcn_global_load_lds(
        (const __attribute__((address_space(1))) void*)(gx + gi),
        (__attribute__((address_space(3))) void*)(smem + it * 64),
        16, 0, 0);
  }
  float2 pe = make_float2(0.f, 0.f);
  if (tile > 0) pe = *((const float2*)gx - 1);   // broadcast
  // ---- load w-parts early: T[c-1] raw + sbuf[g] (SoA) ----
  float4 tw4[5], sb4[5];
  {
    const int cm1 = (chunk > 0) ? chunk - 1 : 0;
    const int jj = cm1 & 7, gg = cm1 >> 3;
    const float4* tvp = (const float4*)t + ((size_t)seq * 8 + jj) * 5 * 512 + gg;
    #pragma unroll
    for (int i = 0; i < 5; i++) tw4[i] = tvp[i * 512];
    const int g = chunk >> 3;
    const float4* sv = (const float4*)sbuf + (size_t)seq * 5 * 512 + g;
    #pragma unroll
    for (int i = 0; i < 5; i++) sb4[i] = sv[i * 512];
  }

  float b0[NB], b1[NB], b2[NB], na1[NB], na2[NB];
  wave_coefs(freqs, gains, qs, b, lane, b0, b1, b2, na1, na2);

  asm volatile("s_waitcnt vmcnt(0) lgkmcnt(0)" ::: "memory");
  __builtin_amdgcn_sched_barrier(0);

  const float* M1 = (const float*)(smem + 1024);         // A^64
  const float* M2 = (const float*)(smem + 1024) + 400;   // A^128
  const float* M4 = (const float*)(smem + 1024) + 800;   // A^256

  // ---- init: segmented KS -> prefix(c-1) ----
  float p[NB], q_[NB];
  {
    float w[20];
    const bool useS = (lanem == 0);
    #pragma unroll
    for (int i = 0; i < 5; i++) {
      float4 a = useS ? sb4[i] : tw4[i];
      w[4*i] = a.x; w[4*i+1] = a.y; w[4*i+2] = a.z; w[4*i+3] = a.w;
    }
    ks_step(w, M1, 1, lanem);
    ks_step(w, M2, 2, lanem);
    ks_step(w, M4, 4, lanem);
    #pragma unroll
    for (int k = 0; k < NB; k++) { p[k] = w[2*k]; q_[k] = w[2*k+1]; }
  }
  // ---- x1/x2 init ----
  float x1, x2;
  if (lane == 0) {
    x1 = pe.y; x2 = pe.x;            // zeros when tile==0
  } else {
    float4 pv = smem[(lane-1)*16 + (15 ^ ((lane-1) & 15))];
    x2 = pv.z; x1 = pv.w;
  }
  // ---- filter ----
  #pragma unroll 2
  for (int qq = 0; qq < 16; qq++) {
    const int slot = lane*16 + (qq ^ (lane & 15));
    float4 xv = smem[slot];
    float xin[4] = {xv.x, xv.y, xv.z, xv.w};
    float o[4];
    #pragma unroll
    for (int j = 0; j < 4; j++) {
      float u = xin[j], u1 = x1, u2 = x2;
      x2 = x1; x1 = xin[j];
      #pragma unroll
      for (int k = 0; k < NB; k++) {
        float v = fmaf(b0[k], u,
                  fmaf(b1[k], u1,
                  fmaf(b2[k], u2,
                  fmaf(na1[k], p[k], na2[k] * q_[k]))));
        u1 = p[k]; u2 = q_[k];
        q_[k] = p[k]; p[k] = v;
        u = v;
      }
      o[j] = u;
    }
    smem[slot] = make_float4(o[0], o[1], o[2], o[3]);
  }
  asm volatile("" ::: "memory");   // keep ds_writes before store-phase reads
  float4* gy = (float4*)(out + (size_t)seq * S_ + (size_t)tile * 4096);
  #pragma unroll 4
  for (int it = 0; it < 16; it++) {
    int f = it * 64 + lane;
    int c = f >> 4, q = f & 15;
    gy[f] = smem[c*16 + (q ^ (c & 15))];
  }
}

// ===========================================================================
extern "C" void kernel_launch(void* const* d_in, const int* in_sizes, int n_in,
                              void* d_out, int out_size, void* d_ws, size_t ws_size,
                              hipStream_t stream) {
  const float* audio = (const float*)d_in[0];
  const float* freqs = (const float*)d_in[1];
  const float* gains = (const float*)d_in[2];
  const float* qs    = (const float*)d_in[3];
  float* out    = (float*)d_out;
  float* t      = (float*)d_ws;                                    // 21 MB
  float* gbuf   = (float*)d_ws + T_FLOATS;                         // 2.6 MB
  float* sbuf   = (float*)d_ws + T_FLOATS + G_FLOATS;              // 2.6 MB
  float* powers = (float*)d_ws + T_FLOATS + 2 * (size_t)G_FLOATS;  // 160 KB

  hipLaunchKernelGGL(pass_head, dim3(F_PCH / F_LCH, SEQ), dim3(64), 0,
                     stream, audio, freqs, gains, qs, t);
  hipLaunchKernelGGL(scan_fold, dim3(F_GRP / 128, SEQ), dim3(128), 0, stream,
                     t, freqs, gains, qs, gbuf, powers);
  hipLaunchKernelGGL(scan_ks2, dim3(SEQ), dim3(512), 0, stream,
                     gbuf, sbuf, freqs, gains, qs);
  hipLaunchKernelGGL(pass_tail, dim3(F_PCH / F_LCH, SEQ), dim3(64), 0,
                     stream, audio, freqs, gains, qs, t, sbuf, powers, out);
}